// Round 1
// baseline (686.390 us; speedup 1.0000x reference)
//
#include <hip/hip_runtime.h>
#include <hip/hip_bf16.h>
#include <stdint.h>

#define T_TOK 8192
#define D_EMB 1024
#define H_DIM 2048
#define N1 4096
#define NE 8

typedef __bf16 bf16_t;
typedef __bf16 bf16x8 __attribute__((ext_vector_type(8)));
typedef __bf16 bf16x4 __attribute__((ext_vector_type(4)));
typedef float f32x4 __attribute__((ext_vector_type(4)));

typedef __attribute__((address_space(1))) void gvoid_t;
typedef __attribute__((address_space(3))) void svoid_t;

__device__ __forceinline__ void gld_lds16(bf16_t* lds, const bf16_t* g) {
  __builtin_amdgcn_global_load_lds((gvoid_t*)g, (svoid_t*)lds, 16, 0, 0);
}

// ---------------- x fp32 -> bf16 ----------------
__global__ __launch_bounds__(256) void k_cvt_x(const float* __restrict__ x,
                                               bf16_t* __restrict__ xb) {
  int i = blockIdx.x * 256 + threadIdx.x;  // 1048576 threads, 8 elems each
  const float4* p = (const float4*)x;
  float4 a = p[i * 2], b = p[i * 2 + 1];
  bf16x8 o;
  o[0] = (bf16_t)a.x; o[1] = (bf16_t)a.y; o[2] = (bf16_t)a.z; o[3] = (bf16_t)a.w;
  o[4] = (bf16_t)b.x; o[5] = (bf16_t)b.y; o[6] = (bf16_t)b.z; o[7] = (bf16_t)b.w;
  *(bf16x8*)(xb + (size_t)i * 8) = o;
}

// ------- weight convert: [E][K][N] fp32 -> [E][N'][K] bf16 (transpose, opt interleave) -------
template <bool ILV>
__global__ __launch_bounds__(256) void k_cvt_w(const float* __restrict__ src,
                                               bf16_t* __restrict__ dst, int K, int N) {
  __shared__ float tile[32][33];
  int e = blockIdx.z;
  int k0 = blockIdx.y << 5, j0 = blockIdx.x << 5;
  const float* s = src + (size_t)e * K * N;
  bf16_t* d = dst + (size_t)e * K * N;
  int t = threadIdx.x;
  int col = t & 31, r0 = t >> 5;
#pragma unroll
  for (int i = 0; i < 4; i++)
    tile[r0 + i * 8][col] = s[(size_t)(k0 + r0 + i * 8) * N + j0 + col];
  __syncthreads();
  int jj = t >> 3, kk0 = (t & 7) << 2;
  int j = j0 + jj, np_;
  if (ILV) {
    int half = N >> 1;
    if (j < half) np_ = ((j >> 4) << 5) | (j & 15);
    else { int jm = j - half; np_ = ((jm >> 4) << 5) | 16 | (jm & 15); }
  } else np_ = j;
  bf16x4 o;
  o[0] = (bf16_t)tile[kk0][jj];     o[1] = (bf16_t)tile[kk0 + 1][jj];
  o[2] = (bf16_t)tile[kk0 + 2][jj]; o[3] = (bf16_t)tile[kk0 + 3][jj];
  *(bf16x4*)(d + (size_t)np_ * K + k0 + kk0) = o;
}

// ---------------- router: scores = x @ wg, top-2, softmax, counts ----------------
__global__ __launch_bounds__(256) void k_router(const float* __restrict__ x,
                                                const float* __restrict__ wg,
                                                int* __restrict__ counts,
                                                int* __restrict__ tki,
                                                float* __restrict__ tkp) {
  __shared__ float wgl[NE * D_EMB];  // transposed [e][d]
  int t = threadIdx.x;
  for (int i = t; i < NE * D_EMB; i += 256) {
    int dd = i >> 3, ee = i & 7;
    wgl[ee * D_EMB + dd] = wg[i];
  }
  __syncthreads();
  int wave = t >> 6, lane = t & 63;
  int tok = (blockIdx.x << 2) + wave;
  const float* xr = x + (size_t)tok * D_EMB;
  float acc[NE] = {};
  for (int d = lane; d < D_EMB; d += 64) {
    float xv = xr[d];
#pragma unroll
    for (int e = 0; e < NE; e++) acc[e] += xv * wgl[e * D_EMB + d];
  }
#pragma unroll
  for (int e = 0; e < NE; e++) {
#pragma unroll
    for (int off = 32; off; off >>= 1) acc[e] += __shfl_xor(acc[e], off);
  }
  if (lane == 0) {
    int i0 = 0; float s0 = acc[0];
#pragma unroll
    for (int e = 1; e < NE; e++) if (acc[e] > s0) { s0 = acc[e]; i0 = e; }
    int i1 = -1; float s1 = -3.4e38f;
#pragma unroll
    for (int e = 0; e < NE; e++) if (e != i0 && acc[e] > s1) { s1 = acc[e]; i1 = e; }
    float ex = __expf(s1 - s0);
    float inv = 1.f / (1.f + ex);
    tki[tok * 2] = i0; tki[tok * 2 + 1] = i1;
    tkp[tok * 2] = inv; tkp[tok * 2 + 1] = ex * inv;
    atomicAdd(&counts[i0], 1); atomicAdd(&counts[i1], 1);
  }
}

__global__ void k_offsets(const int* __restrict__ counts, int* __restrict__ offsets) {
  if (threadIdx.x == 0) {
    int s = 0;
#pragma unroll
    for (int e = 0; e < NE; e++) { offsets[e] = s; s += counts[e]; }
    offsets[NE] = s;
  }
}

__global__ __launch_bounds__(256) void k_scatter(const int* __restrict__ tki,
                                                 const float* __restrict__ tkp,
                                                 const int* __restrict__ offsets,
                                                 int* __restrict__ fill,
                                                 int* __restrict__ tlist,
                                                 float* __restrict__ plist) {
  int tok = blockIdx.x * 256 + threadIdx.x;
  if (tok >= T_TOK) return;
#pragma unroll
  for (int k = 0; k < 2; k++) {
    int e = tki[tok * 2 + k];
    int pos = offsets[e] + atomicAdd(&fill[e], 1);
    tlist[pos] = tok;
    plist[pos] = tkp[tok * 2 + k];
  }
}

// ---------------- grouped GEMM, 128x128 tile, BK=32, 4 waves (2x2), 16x16x32 bf16 MFMA ----
// PHASE 1: A = xb gathered by tlist [.,1024]; B = w12b[e] [4096][1024]; SwiGLU -> hb
// PHASE 2: A = hb contiguous [.,2048];       B = w3b[e]  [1024][2048]; scale+atomicAdd -> out
template <int PHASE>
__global__ __launch_bounds__(256) void k_gemm(const bf16_t* __restrict__ A,
                                              const bf16_t* __restrict__ B,
                                              const int* __restrict__ offsets,
                                              const int* __restrict__ tlist,
                                              const float* __restrict__ plist,
                                              bf16_t* __restrict__ hb,
                                              float* __restrict__ out) {
  constexpr int AK = (PHASE == 1) ? D_EMB : H_DIM;
  const int e = blockIdx.z;
  const int seg = offsets[e];
  const int cnt = offsets[e + 1] - seg;
  const int mt = blockIdx.y;
  if (mt * 128 >= cnt) return;
  const int n0 = blockIdx.x << 7;
  const bf16_t* Bexp = B + (size_t)e * (size_t)AK * ((PHASE == 1) ? N1 : D_EMB);

  __shared__ bf16_t As[128 * 32];
  __shared__ bf16_t Bs[128 * 32];

  const int tid = threadIdx.x;
  const int wave = tid >> 6, lane = tid & 63;

  const bf16_t* a_src[2];
  const bf16_t* b_src[2];
#pragma unroll
  for (int i = 0; i < 2; i++) {
    int o = i * 4096 + wave * 1024 + lane * 16;  // byte offset in 8KB tile
    int r = o >> 6;                              // row (64B = 32 bf16 per row)
    int kc = (o >> 4) & 3;                       // 16B chunk within row
    int rb = mt * 128 + r;
    if (PHASE == 1) {
      int tok = (rb < cnt) ? tlist[seg + rb] : tlist[seg];
      a_src[i] = A + (size_t)tok * AK + kc * 8;
    } else {
      int rowg = (rb < cnt) ? (seg + rb) : seg;
      a_src[i] = A + (size_t)rowg * AK + kc * 8;
    }
    b_src[i] = Bexp + (size_t)(n0 + r) * AK + kc * 8;
  }

  const int wr = wave >> 1, wc = wave & 1;
  const int fr = lane & 15;
  const int fk = (lane >> 4) << 3;

  f32x4 acc[4][4] = {};

  for (int k0 = 0; k0 < AK; k0 += 32) {
    __syncthreads();
#pragma unroll
    for (int i = 0; i < 2; i++) gld_lds16(&As[i * 2048 + wave * 512], a_src[i] + k0);
#pragma unroll
    for (int i = 0; i < 2; i++) gld_lds16(&Bs[i * 2048 + wave * 512], b_src[i] + k0);
    __syncthreads();
#pragma unroll
    for (int mf = 0; mf < 4; mf++) {
      bf16x8 af = *(const bf16x8*)&As[(wr * 64 + mf * 16 + fr) * 32 + fk];
#pragma unroll
      for (int nf = 0; nf < 4; nf++) {
        bf16x8 bfv = *(const bf16x8*)&Bs[(wc * 64 + nf * 16 + fr) * 32 + fk];
        acc[mf][nf] = __builtin_amdgcn_mfma_f32_16x16x32_bf16(af, bfv, acc[mf][nf], 0, 0, 0);
      }
    }
  }

  if (PHASE == 1) {
#pragma unroll
    for (int mf = 0; mf < 4; mf++) {
      int rbase = mt * 128 + wr * 64 + mf * 16 + ((lane >> 4) << 2);
#pragma unroll
      for (int p = 0; p < 2; p++) {
        int hcol = (n0 >> 1) + wc * 32 + p * 16 + fr;
#pragma unroll
        for (int j = 0; j < 4; j++) {
          int r = rbase + j;
          if (r < cnt) {
            float g = acc[mf][2 * p][j];
            float v = acc[mf][2 * p + 1][j];
            float s = g / (1.f + __expf(-g));
            hb[(size_t)(seg + r) * H_DIM + hcol] = (bf16_t)(s * v);
          }
        }
      }
    }
  } else {
#pragma unroll
    for (int mf = 0; mf < 4; mf++) {
      int rbase = mt * 128 + wr * 64 + mf * 16 + ((lane >> 4) << 2);
#pragma unroll
      for (int j = 0; j < 4; j++) {
        int r = rbase + j;
        if (r < cnt) {
          int pos = seg + r;
          int tok = tlist[pos];
          float pr = plist[pos];
          float* op = out + (size_t)tok * D_EMB + n0 + wc * 64 + fr;
#pragma unroll
          for (int nf = 0; nf < 4; nf++)
            atomicAdd(op + nf * 16, pr * acc[mf][nf][j]);
        }
      }
    }
  }
}

extern "C" void kernel_launch(void* const* d_in, const int* in_sizes, int n_in,
                              void* d_out, int out_size, void* d_ws, size_t ws_size,
                              hipStream_t stream) {
  (void)in_sizes; (void)n_in; (void)ws_size;
  const float* x   = (const float*)d_in[0];
  const float* w12 = (const float*)d_in[1];
  const float* w3  = (const float*)d_in[2];
  const float* wg  = (const float*)d_in[3];
  float* out = (float*)d_out;
  char* ws = (char*)d_ws;

  const size_t OFF_XB   = 0;                       // 16,777,216 B
  const size_t OFF_W12B = 16777216;                // 67,108,864 B
  const size_t OFF_W3B  = OFF_W12B + 67108864;     // 33,554,432 B
  const size_t OFF_HB   = OFF_W3B + 33554432;      // 67,108,864 B
  const size_t OFF_META = OFF_HB + 67108864;

  bf16_t* xb   = (bf16_t*)(ws + OFF_XB);
  bf16_t* w12b = (bf16_t*)(ws + OFF_W12B);
  bf16_t* w3b  = (bf16_t*)(ws + OFF_W3B);
  bf16_t* hb   = (bf16_t*)(ws + OFF_HB);
  int*   counts  = (int*)(ws + OFF_META);
  int*   fill    = (int*)(ws + OFF_META + 32);
  int*   offsets = (int*)(ws + OFF_META + 64);
  int*   tki     = (int*)(ws + OFF_META + 128);
  float* tkp     = (float*)(ws + OFF_META + 128 + 65536);
  int*   tlist   = (int*)(ws + OFF_META + 128 + 2 * 65536);
  float* plist   = (float*)(ws + OFF_META + 128 + 3 * 65536);

  hipMemsetAsync(d_out, 0, (size_t)out_size * 4, stream);
  hipMemsetAsync(ws + OFF_META, 0, 64, stream);

  k_cvt_x<<<4096, 256, 0, stream>>>(x, xb);
  k_cvt_w<true ><<<dim3(128, 32, 8), 256, 0, stream>>>(w12, w12b, D_EMB, N1);
  k_cvt_w<false><<<dim3(32, 64, 8), 256, 0, stream>>>(w3, w3b, H_DIM, D_EMB);
  k_router<<<2048, 256, 0, stream>>>(x, wg, counts, tki, tkp);
  k_offsets<<<1, 64, 0, stream>>>(counts, offsets);
  k_scatter<<<32, 256, 0, stream>>>(tki, tkp, offsets, fill, tlist, plist);
  k_gemm<1><<<dim3(32, 64, 8), 256, 0, stream>>>(xb, w12b, offsets, tlist, plist, hb, nullptr);
  k_gemm<2><<<dim3(8, 64, 8), 256, 0, stream>>>(hb, w3b, offsets, tlist, plist, nullptr, out);
}